// Round 9
// baseline (64.068 us; speedup 1.0000x reference)
//
#include <hip/hip_runtime.h>
#include <hip/hip_bf16.h>

#define B_ 32
#define L_ 512
#define H_ 1024
#define E_ 8
#define R_ 16
#define NT_ 1024                 // 16-row tiles over all (b,l)

typedef float f32x4 __attribute__((ext_vector_type(4)));
typedef __bf16 bf16x8 __attribute__((ext_vector_type(8)));

static __device__ __forceinline__ __bf16 f2b(float f) { return (__bf16)f; }

// ---------------- K0: gates = top-2 softmax of x[:,0,:] @ router_w^T -------
__global__ __launch_bounds__(256) void moe_gates_kernel(
    const float* __restrict__ x, const float* __restrict__ rw,
    float* __restrict__ gws)
{
  const int b = blockIdx.x;
  const int t = threadIdx.x;
  const int e = t >> 5;
  const int s = t & 31;
  const float* cls = x + (size_t)b * L_ * H_;
  const float* w   = rw + (size_t)e * H_;
  float p = 0.f;
#pragma unroll
  for (int c = s; c < 256; c += 32) {
    float4 xv = *(const float4*)(cls + 4 * c);
    float4 wv = *(const float4*)(w + 4 * c);
    p += xv.x * wv.x + xv.y * wv.y + xv.z * wv.z + xv.w * wv.w;
  }
#pragma unroll
  for (int off = 16; off; off >>= 1) p += __shfl_down(p, off, 32);
  __shared__ float logits[E_];
  if (s == 0) logits[e] = p;
  __syncthreads();
  if (t == 0) {
    float m0 = -1e30f; int i0 = 0;
    for (int j = 0; j < E_; ++j) if (logits[j] > m0) { m0 = logits[j]; i0 = j; }
    float m1 = -1e30f; int i1 = 0;
    for (int j = 0; j < E_; ++j) if (j != i0 && logits[j] > m1) { m1 = logits[j]; i1 = j; }
    float eb = expf(m1 - m0), inv = 1.f / (1.f + eb);
    gws[b * 4 + 0] = inv;
    gws[b * 4 + 1] = eb * inv;
    ((int*)gws)[b * 4 + 2] = i0;
    ((int*)gws)[b * 4 + 3] = i1;
  }
}

// ---------------- K1: ungated D^T fragments, KS-way K-split ----------------
// Wave w of block `tile` computes K-part q=w over K/KS. Swapped MFMA
// (A=W, B=X) leaves lane holding D[l=r16][p=4gq+j] — dumped raw to ws.
template<int KS>
__global__ __launch_bounds__(64 * KS, 4) void moe_down_kernel(
    const float* __restrict__ x, const float* __restrict__ ldown,
    const float* __restrict__ gws, f32x4* __restrict__ dpart)
{
  const int t    = threadIdx.x;
  const int q    = t >> 6;                  // K-part (= wave id)
  const int lane = t & 63;
  const int gq   = lane >> 4;
  const int r16  = lane & 15;

  const int tile = blockIdx.x;
  const int b    = tile >> 5;
  const int l0   = (tile & 31) * 16;

  const int e0 = ((const int*)gws)[b * 4 + 2];
  const int e1 = ((const int*)gws)[b * 4 + 3];

  const float* xr  = x + ((size_t)b * L_ + l0 + r16) * H_;   // B-frag col r16
  const float* w0p = ldown + ((size_t)e0 * R_ + r16) * H_;   // A-frag row r16
  const float* w1p = ldown + ((size_t)e1 * R_ + r16) * H_;

  f32x4 acc0 = {0.f, 0.f, 0.f, 0.f};
  f32x4 acc1 = {0.f, 0.f, 0.f, 0.f};

  constexpr int NS = (H_ / KS) / 32;        // K-steps in this part
#pragma unroll 8
  for (int s = 0; s < NS; ++s) {
    const int kl = q * (H_ / KS) + s * 32 + 4 * gq;
    float4 xlo = *(const float4*)(xr + kl);
    float4 xhi = *(const float4*)(xr + kl + 16);
    float4 alo = *(const float4*)(w0p + kl);
    float4 ahi = *(const float4*)(w0p + kl + 16);
    float4 blo = *(const float4*)(w1p + kl);
    float4 bhi = *(const float4*)(w1p + kl + 16);
    bf16x8 xq  = { f2b(xlo.x), f2b(xlo.y), f2b(xlo.z), f2b(xlo.w),
                   f2b(xhi.x), f2b(xhi.y), f2b(xhi.z), f2b(xhi.w) };
    bf16x8 wf0 = { f2b(alo.x), f2b(alo.y), f2b(alo.z), f2b(alo.w),
                   f2b(ahi.x), f2b(ahi.y), f2b(ahi.z), f2b(ahi.w) };
    bf16x8 wf1 = { f2b(blo.x), f2b(blo.y), f2b(blo.z), f2b(blo.w),
                   f2b(bhi.x), f2b(bhi.y), f2b(bhi.z), f2b(bhi.w) };
    acc0 = __builtin_amdgcn_mfma_f32_16x16x32_bf16(wf0, xq, acc0, 0, 0, 0);
    acc1 = __builtin_amdgcn_mfma_f32_16x16x32_bf16(wf1, xq, acc1, 0, 0, 0);
  }

  // raw fragment dump: 2 coalesced 1KB stores per wave
  dpart[((size_t)(q * NT_ + tile) * 2 + 0) * 64 + lane] = acc0;
  dpart[((size_t)(q * NT_ + tile) * 2 + 1) * 64 + lane] = acc1;
}

// ---------------- K2: reduce D, gate, out = x + U^T Dg^T (streaming) -------
// 8192 independent waves (8/SIMD): wave = (row-tile rt, col-tile ct of 128 h).
template<int KS>
__global__ __launch_bounds__(256, 8) void moe_up_kernel(
    const float* __restrict__ x, const float* __restrict__ lup,
    const float* __restrict__ gws, const f32x4* __restrict__ dpart,
    float* __restrict__ out)
{
  const int t    = threadIdx.x;
  const int w    = t >> 6;
  const int lane = t & 63;
  const int gq   = lane >> 4;
  const int r16  = lane & 15;

  const int W  = blockIdx.x * 4 + w;
  const int rt = W >> 3;                    // 1024 row-tiles
  const int ct = W & 7;                     // 8 col-tiles of 128 h
  const int b  = rt >> 5;
  const int l0 = (rt & 31) * 16;

  const float g0 = gws[b * 4 + 0];
  const float g1 = gws[b * 4 + 1];
  const int   e0 = ((const int*)gws)[b * 4 + 2];
  const int   e1 = ((const int*)gws)[b * 4 + 3];

  // ---- reduce K-parts (coalesced 1KB loads, L2/L3-hot) + gate + pack ------
  f32x4 d0 = {0.f, 0.f, 0.f, 0.f};
  f32x4 d1 = {0.f, 0.f, 0.f, 0.f};
#pragma unroll
  for (int q = 0; q < KS; ++q) {
    d0 += dpart[((size_t)(q * NT_ + rt) * 2 + 0) * 64 + lane];
    d1 += dpart[((size_t)(q * NT_ + rt) * 2 + 1) * 64 + lane];
  }
  bf16x8 dfrag;
#pragma unroll
  for (int j = 0; j < 4; ++j) {
    dfrag[j]     = f2b(d0[j] * g0);         // B-frag k = 4gq+j     (e0)
    dfrag[4 + j] = f2b(d1[j] * g1);         // B-frag k = 16+4gq+j  (e1)
  }

  const float* u0b = lup + (size_t)e0 * H_ * R_;
  const float* u1b = lup + (size_t)e1 * H_ * R_;
  const float* xr  = x + ((size_t)b * L_ + l0 + r16) * H_;
  float* outr      = out + ((size_t)b * L_ + l0 + r16) * H_;

#pragma unroll
  for (int nt = 0; nt < 8; ++nt) {
    const int h0 = ct * 128 + nt * 16;
    const int ha = h0 + r16;                // A-frag row (h) for this lane
    float4 ulo = *(const float4*)(u0b + (size_t)ha * R_ + 4 * gq);
    float4 uhi = *(const float4*)(u1b + (size_t)ha * R_ + 4 * gq);
    bf16x8 uf = { f2b(ulo.x), f2b(ulo.y), f2b(ulo.z), f2b(ulo.w),
                  f2b(uhi.x), f2b(uhi.y), f2b(uhi.z), f2b(uhi.w) };
    float4 rx = *(const float4*)(xr + h0 + 4 * gq);       // exact f32 residual
    f32x4 acc = { rx.x, rx.y, rx.z, rx.w };
    acc = __builtin_amdgcn_mfma_f32_16x16x32_bf16(uf, dfrag, acc, 0, 0, 0);
    *(float4*)(outr + h0 + 4 * gq) = *(float4*)&acc;
  }
}

extern "C" void kernel_launch(void* const* d_in, const int* in_sizes, int n_in,
                              void* d_out, int out_size, void* d_ws, size_t ws_size,
                              hipStream_t stream) {
  const float* x  = (const float*)d_in[0];
  const float* rw = (const float*)d_in[1];
  const float* ld = (const float*)d_in[2];
  const float* lu = (const float*)d_in[3];
  float* outp = (float*)d_out;

  float* gws   = (float*)d_ws;                          // 512 B gates
  f32x4* dpart = (f32x4*)((char*)d_ws + 1024);          // D fragments

  const size_t per_part = (size_t)NT_ * 2 * 64 * 16;    // 2 MB per K-part

  hipLaunchKernelGGL(moe_gates_kernel, dim3(B_), dim3(256), 0, stream, x, rw, gws);

  if (ws_size >= 1024 + 4 * per_part) {
    hipLaunchKernelGGL(moe_down_kernel<4>, dim3(NT_), dim3(256), 0, stream,
                       x, ld, gws, dpart);
    hipLaunchKernelGGL(moe_up_kernel<4>, dim3(NT_ * 8 / 4), dim3(256), 0, stream,
                       x, lu, gws, dpart, outp);
  } else if (ws_size >= 1024 + 2 * per_part) {
    hipLaunchKernelGGL(moe_down_kernel<2>, dim3(NT_), dim3(128), 0, stream,
                       x, ld, gws, dpart);
    hipLaunchKernelGGL(moe_up_kernel<2>, dim3(NT_ * 8 / 4), dim3(256), 0, stream,
                       x, lu, gws, dpart, outp);
  } else {
    hipLaunchKernelGGL(moe_down_kernel<1>, dim3(NT_), dim3(64), 0, stream,
                       x, ld, gws, dpart);
    hipLaunchKernelGGL(moe_up_kernel<1>, dim3(NT_ * 8 / 4), dim3(256), 0, stream,
                       x, lu, gws, dpart, outp);
  }
}

// Round 10
// 45.087 us; speedup vs baseline: 1.4210x; 1.4210x over previous
//
#include <hip/hip_runtime.h>
#include <hip/hip_bf16.h>

#define B_ 32
#define L_ 512
#define H_ 1024
#define E_ 8
#define R_ 16

typedef float f32x4 __attribute__((ext_vector_type(4)));
typedef __bf16 bf16x8 __attribute__((ext_vector_type(8)));
typedef __bf16 bf16x4 __attribute__((ext_vector_type(4)));

static __device__ __forceinline__ __bf16 f2b(float f) { return (__bf16)f; }

static __device__ __forceinline__ f32x4 MFMA(bf16x8 a, bf16x8 b, f32x4 c) {
  return __builtin_amdgcn_mfma_f32_16x16x32_bf16(a, b, c, 0, 0, 0);
}

// ---------------- gates (fallback path only) -------------------------------
__global__ __launch_bounds__(256) void moe_gates_kernel(
    const float* __restrict__ x, const float* __restrict__ rw,
    float* __restrict__ gws)
{
  const int b = blockIdx.x;
  const int t = threadIdx.x;
  const int e = t >> 5, s = t & 31;
  const float* cls = x + (size_t)b * L_ * H_;
  const float* w   = rw + (size_t)e * H_;
  float p = 0.f;
#pragma unroll
  for (int c = s; c < 256; c += 32) {
    float4 xv = *(const float4*)(cls + 4 * c);
    float4 wv = *(const float4*)(w + 4 * c);
    p += xv.x * wv.x + xv.y * wv.y + xv.z * wv.z + xv.w * wv.w;
  }
#pragma unroll
  for (int off = 16; off; off >>= 1) p += __shfl_down(p, off, 32);
  __shared__ float logits[E_];
  if (s == 0) logits[e] = p;
  __syncthreads();
  if (t == 0) {
    float m0 = -1e30f; int i0 = 0;
    for (int j = 0; j < E_; ++j) if (logits[j] > m0) { m0 = logits[j]; i0 = j; }
    float m1 = -1e30f; int i1 = 0;
    for (int j = 0; j < E_; ++j) if (j != i0 && logits[j] > m1) { m1 = logits[j]; i1 = j; }
    float eb = expf(m1 - m0), inv = 1.f / (1.f + eb);
    gws[b * 4 + 0] = inv;
    gws[b * 4 + 1] = eb * inv;
    ((int*)gws)[b * 4 + 2] = i0;
    ((int*)gws)[b * 4 + 3] = i1;
  }
}

// ---------------- prep: f32 weights -> bf16 in ws; + gates -----------------
__global__ __launch_bounds__(256) void moe_prep_kernel(
    const float* __restrict__ x, const float* __restrict__ rw,
    const float* __restrict__ ldown, const float* __restrict__ lup,
    __bf16* __restrict__ ldb, __bf16* __restrict__ lub,
    float* __restrict__ gws)
{
  const int bid = blockIdx.x;
  if (bid < 256) {                          // weight conversion: 2x131072 f32
    const int base = bid * 1024 + threadIdx.x * 4;
    const float* src; __bf16* dst; int off;
    if (base < 131072) { src = ldown; dst = ldb; off = base; }
    else               { src = lup;   dst = lub; off = base - 131072; }
    float4 v = *(const float4*)(src + off);
    bf16x4 bv = { f2b(v.x), f2b(v.y), f2b(v.z), f2b(v.w) };
    *(bf16x4*)(dst + off) = bv;
    return;
  }
  // gates for b = bid - 256
  const int b = bid - 256;
  const int t = threadIdx.x;
  const int e = t >> 5, s = t & 31;
  const float* cls = x + (size_t)b * L_ * H_;
  const float* w   = rw + (size_t)e * H_;
  float p = 0.f;
#pragma unroll
  for (int c = s; c < 256; c += 32) {
    float4 xv = *(const float4*)(cls + 4 * c);
    float4 wv = *(const float4*)(w + 4 * c);
    p += xv.x * wv.x + xv.y * wv.y + xv.z * wv.z + xv.w * wv.w;
  }
#pragma unroll
  for (int off = 16; off; off >>= 1) p += __shfl_down(p, off, 32);
  __shared__ float logits[E_];
  if (s == 0) logits[e] = p;
  __syncthreads();
  if (t == 0) {
    float m0 = -1e30f; int i0 = 0;
    for (int j = 0; j < E_; ++j) if (logits[j] > m0) { m0 = logits[j]; i0 = j; }
    float m1 = -1e30f; int i1 = 0;
    for (int j = 0; j < E_; ++j) if (j != i0 && logits[j] > m1) { m1 = logits[j]; i1 = j; }
    float eb = expf(m1 - m0), inv = 1.f / (1.f + eb);
    gws[b * 4 + 0] = inv;
    gws[b * 4 + 1] = eb * inv;
    ((int*)gws)[b * 4 + 2] = i0;
    ((int*)gws)[b * 4 + 3] = i1;
  }
}

// ---------------- main: 512 thr / 8 waves; K-split-8 phase A; h-split B ----
// Phase A (swapped operands, R8/R9-proven): lane holds D^T frag with
// col(lane&15)=l, row(4*(lane>>4)+j)=p. Reduce 8 K-parts in LDS, gate, pack
// dg[l][p]. Phase B: wave w covers h in [w*128,(w+1)*128); transposed MFMA
// (A=U^T rows h, B=Dg^T), residual = bf16 xs quad, float4 stores.
template<int BW>
__global__ __launch_bounds__(512, 4) void moe_main_kernel(
    const float* __restrict__ x,
    const __bf16* __restrict__ ldb, const __bf16* __restrict__ lub,
    const float* __restrict__ ldf, const float* __restrict__ luf,
    const float* __restrict__ gws, float* __restrict__ out)
{
  __shared__ __bf16 xs[16][1032];           // 33,024 B
  __shared__ f32x4  red[8][2][64];          // 16,384 B
  __shared__ __bf16 dg[16][40];             //  1,280 B

  const int t    = threadIdx.x;
  const int w    = t >> 6;                  // 0..7
  const int lane = t & 63;
  const int gq   = lane >> 4;
  const int r16  = lane & 15;

  const int bid  = blockIdx.x;
  const int tile = (bid & 7) * 128 + (bid >> 3);   // XCD swizzle (bijective)
  const int b    = tile >> 5;
  const int l0   = (tile & 31) * 16;

  const float g0 = gws[b * 4 + 0];
  const float g1 = gws[b * 4 + 1];
  const int   e0 = ((const int*)gws)[b * 4 + 2];
  const int   e1 = ((const int*)gws)[b * 4 + 3];

  const float* xb = x + ((size_t)b * L_ + l0) * H_;

  // ---- stage X tile as bf16 (wave w: rows 2w,2w+1; 16 indep loads) --------
  {
    const int row = 2 * w + (lane >> 5);
    const int c0  = (lane & 31) * 4;
    const float* xr = xb + (size_t)row * H_;
#pragma unroll
    for (int i = 0; i < 8; ++i) {
      float4 v = *(const float4*)(xr + c0 + i * 128);
      bf16x4 bv = { f2b(v.x), f2b(v.y), f2b(v.z), f2b(v.w) };
      *(bf16x4*)&xs[row][c0 + i * 128] = bv;
    }
  }
  __syncthreads();

  // ---- Phase A: wave w handles K slice [w*128, w*128+128) -----------------
  f32x4 acc0 = {0.f, 0.f, 0.f, 0.f};
  f32x4 acc1 = {0.f, 0.f, 0.f, 0.f};
#pragma unroll
  for (int s = 0; s < 4; ++s) {
    const int kl = w * 128 + s * 32 + 4 * gq;
    bf16x4 xlo = *(const bf16x4*)&xs[r16][kl];
    bf16x4 xhi = *(const bf16x4*)&xs[r16][kl + 16];
    bf16x8 xq = { xlo[0], xlo[1], xlo[2], xlo[3],
                  xhi[0], xhi[1], xhi[2], xhi[3] };
    bf16x8 wf0, wf1;
    if constexpr (BW) {
      const __bf16* w0p = ldb + ((size_t)e0 * R_ + r16) * H_;
      const __bf16* w1p = ldb + ((size_t)e1 * R_ + r16) * H_;
      bf16x4 a0 = *(const bf16x4*)(w0p + kl);
      bf16x4 a1 = *(const bf16x4*)(w0p + kl + 16);
      bf16x4 b0 = *(const bf16x4*)(w1p + kl);
      bf16x4 b1 = *(const bf16x4*)(w1p + kl + 16);
      wf0 = bf16x8{ a0[0],a0[1],a0[2],a0[3], a1[0],a1[1],a1[2],a1[3] };
      wf1 = bf16x8{ b0[0],b0[1],b0[2],b0[3], b1[0],b1[1],b1[2],b1[3] };
    } else {
      const float* w0p = ldf + ((size_t)e0 * R_ + r16) * H_;
      const float* w1p = ldf + ((size_t)e1 * R_ + r16) * H_;
      float4 alo = *(const float4*)(w0p + kl);
      float4 ahi = *(const float4*)(w0p + kl + 16);
      float4 blo = *(const float4*)(w1p + kl);
      float4 bhi = *(const float4*)(w1p + kl + 16);
      wf0 = bf16x8{ f2b(alo.x), f2b(alo.y), f2b(alo.z), f2b(alo.w),
                    f2b(ahi.x), f2b(ahi.y), f2b(ahi.z), f2b(ahi.w) };
      wf1 = bf16x8{ f2b(blo.x), f2b(blo.y), f2b(blo.z), f2b(blo.w),
                    f2b(bhi.x), f2b(bhi.y), f2b(bhi.z), f2b(bhi.w) };
    }
    acc0 = MFMA(wf0, xq, acc0);
    acc1 = MFMA(wf1, xq, acc1);
  }
  red[w][0][lane] = acc0;
  red[w][1][lane] = acc1;
  __syncthreads();

  // ---- reduce 8 K-parts + gate + pack dg[l][p] ----------------------------
  // D^T frag layout: l = slot&15 (col), p = 4*(slot>>4)+j (row).
  if (t < 128) {
    const int tl = t >> 6, slot = t & 63;
    f32x4 v = red[0][tl][slot];
#pragma unroll
    for (int q = 1; q < 8; ++q) v += red[q][tl][slot];
    const float g = tl ? g1 : g0;
    const int l  = slot & 15;
    const int p0 = tl * 16 + (slot >> 4) * 4;
#pragma unroll
    for (int j = 0; j < 4; ++j) dg[l][p0 + j] = f2b(v[j] * g);
  }
  __syncthreads();

  // ---- Phase B: wave w covers h in [w*128, (w+1)*128) ---------------------
  bf16x8 dfrag;
#pragma unroll
  for (int j = 0; j < 4; ++j) {
    dfrag[j]     = dg[r16][4 * gq + j];         // k=4gq+j      (e0)
    dfrag[4 + j] = dg[r16][16 + 4 * gq + j];    // k=16+4gq+j   (e1)
  }

  float* outr = out + ((size_t)b * L_ + l0 + r16) * H_;

#pragma unroll
  for (int nt = 0; nt < 8; ++nt) {
    const int h0 = w * 128 + nt * 16;
    const int ha = h0 + r16;
    bf16x8 uf;
    if constexpr (BW) {
      bf16x4 ulo = *(const bf16x4*)(lub + ((size_t)e0 * H_ + ha) * R_ + 4 * gq);
      bf16x4 uhi = *(const bf16x4*)(lub + ((size_t)e1 * H_ + ha) * R_ + 4 * gq);
      uf = bf16x8{ ulo[0],ulo[1],ulo[2],ulo[3], uhi[0],uhi[1],uhi[2],uhi[3] };
    } else {
      float4 ulo = *(const float4*)(luf + ((size_t)e0 * H_ + ha) * R_ + 4 * gq);
      float4 uhi = *(const float4*)(luf + ((size_t)e1 * H_ + ha) * R_ + 4 * gq);
      uf = bf16x8{ f2b(ulo.x), f2b(ulo.y), f2b(ulo.z), f2b(ulo.w),
                   f2b(uhi.x), f2b(uhi.y), f2b(uhi.z), f2b(uhi.w) };
    }
    bf16x4 rx = *(const bf16x4*)&xs[r16][h0 + 4 * gq];    // bf16 residual
    f32x4 acc = { (float)rx[0], (float)rx[1], (float)rx[2], (float)rx[3] };
    acc = MFMA(uf, dfrag, acc);
    *(float4*)(outr + h0 + 4 * gq) = *(float4*)&acc;
  }
}

extern "C" void kernel_launch(void* const* d_in, const int* in_sizes, int n_in,
                              void* d_out, int out_size, void* d_ws, size_t ws_size,
                              hipStream_t stream) {
  const float* x  = (const float*)d_in[0];
  const float* rw = (const float*)d_in[1];
  const float* ld = (const float*)d_in[2];
  const float* lu = (const float*)d_in[3];
  float* outp = (float*)d_out;

  float*  gws = (float*)d_ws;                         // 512 B
  __bf16* ldb = (__bf16*)((char*)d_ws + 1024);        // 256 KB
  __bf16* lub = ldb + 131072;                         // 256 KB

  if (ws_size >= 1024 + 2 * 131072 * sizeof(__bf16)) {
    hipLaunchKernelGGL(moe_prep_kernel, dim3(256 + B_), dim3(256), 0, stream,
                       x, rw, ld, lu, ldb, lub, gws);
    hipLaunchKernelGGL(moe_main_kernel<1>, dim3(1024), dim3(512), 0, stream,
                       x, ldb, lub, nullptr, nullptr, gws, outp);
  } else {
    hipLaunchKernelGGL(moe_gates_kernel, dim3(B_), dim3(256), 0, stream,
                       x, rw, gws);
    hipLaunchKernelGGL(moe_main_kernel<0>, dim3(1024), dim3(512), 0, stream,
                       x, nullptr, nullptr, ld, lu, gws, outp);
  }
}